// Round 2
// baseline (563.969 us; speedup 1.0000x reference)
//
#include <hip/hip_runtime.h>

// Problem constants (fixed by the reference file)
#define B_   32
#define Q_   512
#define R_   1024
#define D_   2048
#define L_   1536          // Q + R
#define NROW (B_ * 1025)   // rows l in [Q-1, L-1] per batch = 1025 rows -> 32800

// Output layout (tuple flattened in return order, all as float32)
#define O_VALUES 0
#define O_VPM    32768
#define O_VLP    65536
#define O_SC     65568
#define O_RLP    65600
#define O_KL     65632
#define O_KLR    98400
#define O_ADV    131168
#define O_RET    163936

// meta layout (ints, in d_ws after the two dot arrays):
// [0] = byteMode flag; [1+b] = rlp[b]; [33+b] = vlp[b]; [65+b] = anyPad[b];
// [97+b] = lim[b] = rlp[b]+1 (max row index i needed in k_dots)
#define M_FLAG 0
#define M_RLP  1
#define M_VLP  33
#define M_PAD  65
#define M_LIM  97

// ---------------------------------------------------------------------------
// K0: mask analysis. One block. Detects mask storage (byte vs int32) and
// computes rlp/vlp/anyPad/lim per batch so k_dots can skip unneeded rows.
// ---------------------------------------------------------------------------
__global__ __launch_bounds__(1024) void k_prep(
    const void* __restrict__ maskraw,
    int* __restrict__ meta)
{
    __shared__ int sflag;
    const int tid = threadIdx.x;
    if (tid == 0) sflag = 0;
    __syncthreads();

    // byte-bool vs int32 detection: reading 8192 uint32s is in-bounds either
    // way; int32 bools are 0/1 so high 3 bytes of each word are 0; byte bools
    // place a '1' at a misaligned byte for any row with len < 1024.
    const unsigned int* mu = (const unsigned int*)maskraw;
    bool odd = false;
    for (int j = tid; j < (B_ * R_) / 4; j += 1024)
        odd |= (mu[j] & 0xFFFFFF00u) != 0u;
    if (odd) atomicOr(&sflag, 1);
    __syncthreads();
    const int byteMode = sflag;

    const int w = tid >> 6, lane = tid & 63;
    for (int p = 0; p < 2; ++p) {
        const int b = w + 16 * p;
        const int base = b * R_ + lane * 16;
        int  ll   = -1;
        bool anyT = false;
        if (byteMode) {
            const unsigned char* mb = (const unsigned char*)maskraw;
#pragma unroll
            for (int j = 0; j < 16; ++j) {
                const bool m = mb[base + j] != 0;
                if (!m) ll = lane * 16 + j;
                anyT |= m;
            }
        } else {
            const int* mi = (const int*)maskraw;
#pragma unroll
            for (int j = 0; j < 16; ++j) {
                const bool m = mi[base + j] != 0;
                if (!m) ll = lane * 16 + j;
                anyT |= m;
            }
        }
#pragma unroll
        for (int d = 1; d < 64; d <<= 1) {
            int o = __shfl_xor(ll, d, 64);
            ll = ll > o ? ll : o;
        }
        const int  rlp    = ll < 0 ? 0 : ll;
        const bool anyPad = (__ballot(anyT) != 0ull);
        const int  vlp    = (rlp > 0 && rlp < R_ - 1) ? rlp + 1 : rlp;
        if (lane == 0) {
            meta[M_RLP + b] = rlp;
            meta[M_VLP + b] = vlp;
            meta[M_PAD + b] = anyPad ? 1 : 0;
            meta[M_LIM + b] = rlp + 1;   // score needs i = rlp+1; values need i <= rlp and i = vlp <= rlp+1
        }
    }
    if (tid == 0) meta[M_FLAG] = byteMode;
}

// ---------------------------------------------------------------------------
// K1: fused dual GEMV with row skipping. Row i of batch b (l = 511+i) is
// loaded only if i <= lim[b]; padded-tail rows are never consumed downstream.
// One wave per row, 64 lanes x 8 float4. Weights register-resident.
// ---------------------------------------------------------------------------
__global__ __launch_bounds__(256) void k_dots(
    const float* __restrict__ hidden,
    const float* __restrict__ wb,
    const float* __restrict__ wa,
    const int*   __restrict__ meta,
    float* __restrict__ vals_dot,     // NROW: dot with (w_base + w_adapter)
    float* __restrict__ scores_dot)   // NROW: dot with w_base
{
    const int lane = threadIdx.x & 63;
    const int wid  = blockIdx.x * 4 + (threadIdx.x >> 6);
    const int nw   = gridDim.x * 4;

    const float4* wb4 = (const float4*)wb;
    const float4* wa4 = (const float4*)wa;
    float4 vb[8], vs[8];
#pragma unroll
    for (int k = 0; k < 8; ++k) {
        float4 bv = wb4[lane + 64 * k];
        float4 av = wa4[lane + 64 * k];
        vb[k] = bv;
        vs[k] = make_float4(bv.x + av.x, bv.y + av.y, bv.z + av.z, bv.w + av.w);
    }

    for (int row = wid; row < NROW; row += nw) {
        const int bb = row / 1025;
        const int i  = row - bb * 1025;
        if (i > meta[M_LIM + bb]) continue;   // unneeded padded-tail row
        const float4* hp =
            (const float4*)(hidden + ((size_t)bb * L_ + 511 + i) * (size_t)D_);
        float4 h[8];
#pragma unroll
        for (int k = 0; k < 8; ++k) h[k] = hp[lane + 64 * k];
        float db = 0.f, ds = 0.f;
#pragma unroll
        for (int k = 0; k < 8; ++k) {
            db += h[k].x * vb[k].x + h[k].y * vb[k].y + h[k].z * vb[k].z + h[k].w * vb[k].w;
            ds += h[k].x * vs[k].x + h[k].y * vs[k].y + h[k].z * vs[k].z + h[k].w * vs[k].w;
        }
#pragma unroll
        for (int d = 32; d > 0; d >>= 1) {
            db += __shfl_down(db, d, 64);
            ds += __shfl_down(ds, d, 64);
        }
        if (lane == 0) { vals_dot[row] = ds; scores_dot[row] = db; }
    }
}

// ---------------------------------------------------------------------------
// K2: fused epilogue — per-batch logic + GAE + whiten, one block of 16 waves.
// Wave w handles batches w and w+16. Whiten stats reduce through LDS; the
// advantages are whitened from registers and written exactly once.
// ---------------------------------------------------------------------------
__global__ __launch_bounds__(1024) void k_seq2(
    const float* __restrict__ vals_dot,
    const float* __restrict__ scores_dot,
    const float* __restrict__ gen,
    const float* __restrict__ ref,
    const void*  __restrict__ maskraw,
    const int*   __restrict__ meta,
    float* __restrict__ out)
{
    __shared__ double red0[16], red1[16], red2[16];
    __shared__ float  smean, srs;

    const int tid  = threadIdx.x;
    const int w    = tid >> 6, lane = tid & 63;
    const int byteMode = meta[M_FLAG];

    const float c  = 0.99f * 0.95f;
    const float c2 = c * c, c4 = c2 * c2, c8 = c4 * c4, c16 = c8 * c8;

    float        aP[2][16];
    unsigned int pm[2];
    double sx = 0.0, sx2 = 0.0, nn = 0.0;

    for (int p = 0; p < 2; ++p) {
        const int b      = w + 16 * p;
        const int rlp    = meta[M_RLP + b];
        const int vlp    = meta[M_VLP + b];
        const int anyPad = meta[M_PAD + b];
        const int base   = b * R_ + lane * 16;

        unsigned int mbits = 0;
        if (byteMode) {
            const unsigned char* mb = (const unsigned char*)maskraw;
#pragma unroll
            for (int j = 0; j < 16; ++j) mbits |= (mb[base + j] ? 1u : 0u) << j;
        } else {
            const int* mi = (const int*)maskraw;
#pragma unroll
            for (int j = 0; j < 16; ++j) mbits |= (mi[base + j] ? 1u : 0u) << j;
        }
        pm[p] = mbits;

        const float score = anyPad ? scores_dot[b * 1025 + rlp + 1] : -3.0f;

        float v[16], dl[16];
#pragma unroll
        for (int j = 0; j < 16; ++j) {
            const int  t   = lane * 16 + j;
            const bool mj  = (mbits >> j) & 1u;
            const bool vpm = mj && (t != vlp);
            const float vv = vpm ? 0.f : vals_dot[b * 1025 + t];
            v[j] = vv;
            out[O_VALUES + b * R_ + t] = vv;
            out[O_VPM + b * R_ + t]    = vpm ? 1.f : 0.f;
        }
        float tsh = __shfl_down(v[0], 1, 64);
        const float vnh = (lane == 63) ? 0.f : tsh;

#pragma unroll
        for (int j = 0; j < 16; ++j) {
            const int t = lane * 16 + j;
            const float kl = gen[b * R_ + t] - ref[b * R_ + t];
            out[O_KL + b * R_ + t] = kl;
            const float klr = -0.1f * kl;
            out[O_KLR + b * R_ + t] = klr;
            const float rw = klr + ((t == vlp) ? score : 0.f);
            const float vn = (j < 15) ? v[j + 1] : vnh;
            dl[j] = rw + 0.99f * vn - v[j];
        }

        // local reverse scan, zero carry
        float a[16];
        a[15] = dl[15];
#pragma unroll
        for (int j = 14; j >= 0; --j) a[j] = dl[j] + c * a[j + 1];

        // cross-lane weighted suffix scan of chunk heads (factor c^16)
        float S = a[0], f = c16;
#pragma unroll
        for (int d = 1; d < 64; d <<= 1) {
            float up = __shfl_down(S, d, 64);
            up = (lane + d < 64) ? up : 0.f;
            S += f * up;
            f *= f;
        }
        float t1 = __shfl_down(S, 1, 64);
        float carry = (lane == 63) ? 0.f : t1;
#pragma unroll
        for (int j = 15; j >= 0; --j) { a[j] = dl[j] + c * carry; carry = a[j]; }

#pragma unroll
        for (int j = 0; j < 16; ++j) {
            const int t = lane * 16 + j;
            out[O_RET + b * R_ + t] = a[j] + v[j];
            aP[p][j] = a[j];
            if (!((mbits >> j) & 1u)) {
                sx  += (double)a[j];
                sx2 += (double)a[j] * (double)a[j];
                nn  += 1.0;
            }
        }
        if (lane == 0) {
            out[O_VLP + b] = (float)vlp;
            out[O_SC + b]  = score;
            out[O_RLP + b] = (float)rlp;
        }
    }

    // wave-level reduction of whiten partials
#pragma unroll
    for (int d = 1; d < 64; d <<= 1) {
        sx  += __shfl_xor(sx, d, 64);
        sx2 += __shfl_xor(sx2, d, 64);
        nn  += __shfl_xor(nn, d, 64);
    }
    if (lane == 0) { red0[w] = sx; red1[w] = sx2; red2[w] = nn; }
    __syncthreads();
    if (tid == 0) {
        double SX = 0.0, SX2 = 0.0, N = 0.0;
        for (int i = 0; i < 16; ++i) { SX += red0[i]; SX2 += red1[i]; N += red2[i]; }
        const double mean = SX / N;
        const double var  = (SX2 - SX * SX / N) / (N - 1.0);
        smean = (float)mean;
        srs   = (float)(1.0 / sqrt(var + 1e-8));
    }
    __syncthreads();
    const float mean = smean, rsc = srs;

    for (int p = 0; p < 2; ++p) {
        const int b = w + 16 * p;
#pragma unroll
        for (int j = 0; j < 16; ++j) {
            const int t = lane * 16 + j;
            const bool mj = (pm[p] >> j) & 1u;
            out[O_ADV + b * R_ + t] = mj ? 0.f : (aP[p][j] - mean) * rsc;
        }
    }
}

extern "C" void kernel_launch(void* const* d_in, const int* in_sizes, int n_in,
                              void* d_out, int out_size, void* d_ws, size_t ws_size,
                              hipStream_t stream) {
    const float* hidden = (const float*)d_in[0];
    const float* wb     = (const float*)d_in[1];
    const float* wa     = (const float*)d_in[2];
    const float* gen    = (const float*)d_in[3];
    const float* ref    = (const float*)d_in[4];
    const void*  mask   = d_in[5];
    // d_in[6] = queries_len (constant 512, baked in)

    float* out = (float*)d_out;
    float* wsf = (float*)d_ws;
    float* vals_dot   = wsf;
    float* scores_dot = wsf + NROW;
    int*   meta       = (int*)((char*)d_ws + (size_t)2 * NROW * sizeof(float));

    hipLaunchKernelGGL(k_prep, dim3(1), dim3(1024), 0, stream, mask, meta);
    hipLaunchKernelGGL(k_dots, dim3(2048), dim3(256), 0, stream,
                       hidden, wb, wa, meta, vals_dot, scores_dot);
    hipLaunchKernelGGL(k_seq2, dim3(1), dim3(1024), 0, stream,
                       vals_dot, scores_dot, gen, ref, mask, meta, out);
}

// Round 3
// 492.425 us; speedup vs baseline: 1.1453x; 1.1453x over previous
//
#include <hip/hip_runtime.h>

// Problem constants (fixed by the reference file)
#define B_   32
#define Q_   512
#define R_   1024
#define D_   2048
#define L_   1536          // Q + R
#define NROW (B_ * 1025)   // rows l in [Q-1, L-1] per batch = 1025 rows

// Output layout (tuple flattened in return order, all float32)
#define O_VALUES 0
#define O_VPM    32768
#define O_VLP    65536
#define O_SC     65568
#define O_RLP    65600
#define O_KL     65632
#define O_KLR    98400
#define O_ADV    131168
#define O_RET    163936

// meta layout (ints): [0]=byteMode; [1+b]=rlp; [33+b]=vlp; [65+b]=anyPad; [97+b]=lim
#define M_FLAG 0
#define M_RLP  1
#define M_VLP  33
#define M_PAD  65
#define M_LIM  97

// ---------------------------------------------------------------------------
// K0: mask analysis (1 block). Detect byte-bool vs int32 storage, compute
// rlp/vlp/anyPad/lim per batch.
// ---------------------------------------------------------------------------
__global__ __launch_bounds__(1024) void k_prep(
    const void* __restrict__ maskraw,
    int* __restrict__ meta)
{
    __shared__ int sflag;
    const int tid = threadIdx.x;
    if (tid == 0) sflag = 0;
    __syncthreads();

    // int32 bools are 0/1 -> high 3 bytes of each word zero; byte bools place
    // a set byte at a misaligned position for any row with len < 1024.
    const unsigned int* mu = (const unsigned int*)maskraw;
    bool odd = false;
    for (int j = tid; j < (B_ * R_) / 4; j += 1024)
        odd |= (mu[j] & 0xFFFFFF00u) != 0u;
    if (odd) atomicOr(&sflag, 1);
    __syncthreads();
    const int byteMode = sflag;

    const int w = tid >> 6, lane = tid & 63;
    for (int p = 0; p < 2; ++p) {
        const int b = w + 16 * p;
        const int base = b * R_ + lane * 16;
        int  ll   = -1;
        bool anyT = false;
        if (byteMode) {
            const unsigned char* mb = (const unsigned char*)maskraw;
#pragma unroll
            for (int j = 0; j < 16; ++j) {
                const bool m = mb[base + j] != 0;
                if (!m) ll = lane * 16 + j;
                anyT |= m;
            }
        } else {
            const int* mi = (const int*)maskraw;
#pragma unroll
            for (int j = 0; j < 16; ++j) {
                const bool m = mi[base + j] != 0;
                if (!m) ll = lane * 16 + j;
                anyT |= m;
            }
        }
#pragma unroll
        for (int d = 1; d < 64; d <<= 1) {
            int o = __shfl_xor(ll, d, 64);
            ll = ll > o ? ll : o;
        }
        const int  rlp    = ll < 0 ? 0 : ll;
        const bool anyPad = (__ballot(anyT) != 0ull);
        const int  vlp    = (rlp > 0 && rlp < R_ - 1) ? rlp + 1 : rlp;
        if (lane == 0) {
            meta[M_RLP + b] = rlp;
            meta[M_VLP + b] = vlp;
            meta[M_PAD + b] = anyPad ? 1 : 0;
            meta[M_LIM + b] = rlp + 1;  // max row index i consumed downstream
        }
    }
    if (tid == 0) meta[M_FLAG] = byteMode;
}

// ---------------------------------------------------------------------------
// K1: fused dual GEMV, batch-major wave mapping. Wave wid -> batch wid>>8,
// slot widx = wid&255; rows i = widx, widx+256, ... while i <= lim[batch].
// lim loaded ONCE per wave; trip count wave-uniform; skipped tail rows are
// never read. One wave per row-slice, 64 lanes x 8 float4; weights in regs.
// ---------------------------------------------------------------------------
__global__ __launch_bounds__(256) void k_dots(
    const float* __restrict__ hidden,
    const float* __restrict__ wb,
    const float* __restrict__ wa,
    const int*   __restrict__ meta,
    float* __restrict__ vals_dot,     // NROW: dot with (w_base + w_adapter)
    float* __restrict__ scores_dot)   // NROW: dot with w_base
{
    const int lane = threadIdx.x & 63;
    const int wid  = blockIdx.x * 4 + (threadIdx.x >> 6);   // 0..8191
    const int bb   = wid >> 8;                              // 0..31
    const int widx = wid & 255;

    const int lim = meta[M_LIM + bb];   // one load per wave

    const float4* wb4 = (const float4*)wb;
    const float4* wa4 = (const float4*)wa;
    float4 vb[8], vs[8];
#pragma unroll
    for (int k = 0; k < 8; ++k) {
        float4 bv = wb4[lane + 64 * k];
        float4 av = wa4[lane + 64 * k];
        vb[k] = bv;
        vs[k] = make_float4(bv.x + av.x, bv.y + av.y, bv.z + av.z, bv.w + av.w);
    }

    for (int i = widx; i <= lim; i += 256) {
        const float4* hp =
            (const float4*)(hidden + ((size_t)bb * L_ + 511 + i) * (size_t)D_);
        float4 h[8];
#pragma unroll
        for (int k = 0; k < 8; ++k) h[k] = hp[lane + 64 * k];
        float db = 0.f, ds = 0.f;
#pragma unroll
        for (int k = 0; k < 8; ++k) {
            db += h[k].x * vb[k].x + h[k].y * vb[k].y + h[k].z * vb[k].z + h[k].w * vb[k].w;
            ds += h[k].x * vs[k].x + h[k].y * vs[k].y + h[k].z * vs[k].z + h[k].w * vs[k].w;
        }
#pragma unroll
        for (int d = 32; d > 0; d >>= 1) {
            db += __shfl_down(db, d, 64);
            ds += __shfl_down(ds, d, 64);
        }
        if (lane == 0) {
            const int row = bb * 1025 + i;
            vals_dot[row] = ds;
            scores_dot[row] = db;
        }
    }
}

// ---------------------------------------------------------------------------
// K2: per-batch logic + GAE (one wave per batch, 32 blocks). Writes raw
// advantages; whiten partials accumulated into acc via device atomics.
// ---------------------------------------------------------------------------
__global__ __launch_bounds__(64) void k_seq(
    const float* __restrict__ vals_dot,
    const float* __restrict__ scores_dot,
    const float* __restrict__ gen,
    const float* __restrict__ ref,
    const void*  __restrict__ maskraw,
    const int*   __restrict__ meta,
    float* __restrict__ out,
    double* __restrict__ acc)     // [sum_x, sum_x2, n], pre-zeroed
{
    const int b    = blockIdx.x;
    const int lane = threadIdx.x;
    const int byteMode = meta[M_FLAG];
    const int rlp    = meta[M_RLP + b];
    const int vlp    = meta[M_VLP + b];
    const int anyPad = meta[M_PAD + b];

    const int base = b * R_ + lane * 16;
    unsigned int mbits = 0;
    if (byteMode) {
        const unsigned char* mb = (const unsigned char*)maskraw;
#pragma unroll
        for (int j = 0; j < 16; ++j) mbits |= (mb[base + j] ? 1u : 0u) << j;
    } else {
        const int* mi = (const int*)maskraw;
#pragma unroll
        for (int j = 0; j < 16; ++j) mbits |= (mi[base + j] ? 1u : 0u) << j;
    }

    const float score = anyPad ? scores_dot[b * 1025 + rlp + 1] : -3.0f;

    float v[16];
#pragma unroll
    for (int j = 0; j < 16; ++j) {
        const int  t   = lane * 16 + j;
        const bool mj  = (mbits >> j) & 1u;
        const bool vpm = mj && (t != vlp);
        const float vv = vpm ? 0.f : vals_dot[b * 1025 + t];
        v[j] = vv;
        out[O_VALUES + b * R_ + t] = vv;
        out[O_VPM + b * R_ + t]    = vpm ? 1.f : 0.f;
    }
    float tsh = __shfl_down(v[0], 1, 64);
    const float vnh = (lane == 63) ? 0.f : tsh;

    const float c = 0.99f * 0.95f;
    float dl[16];
#pragma unroll
    for (int j = 0; j < 16; ++j) {
        const int t = lane * 16 + j;
        const float kl = gen[b * R_ + t] - ref[b * R_ + t];
        out[O_KL + b * R_ + t]  = kl;
        const float klr = -0.1f * kl;
        out[O_KLR + b * R_ + t] = klr;
        const float rw = klr + ((t == vlp) ? score : 0.f);
        const float vn = (j < 15) ? v[j + 1] : vnh;
        dl[j] = rw + 0.99f * vn - v[j];
    }

    // local reverse scan, zero carry
    float a[16];
    a[15] = dl[15];
#pragma unroll
    for (int j = 14; j >= 0; --j) a[j] = dl[j] + c * a[j + 1];

    // cross-lane weighted suffix scan of chunk heads (factor c^16)
    const float c2 = c * c, c4 = c2 * c2, c8 = c4 * c4, c16 = c8 * c8;
    float S = a[0], f = c16;
#pragma unroll
    for (int d = 1; d < 64; d <<= 1) {
        float up = __shfl_down(S, d, 64);
        up = (lane + d < 64) ? up : 0.f;
        S += f * up;
        f *= f;
    }
    float t1 = __shfl_down(S, 1, 64);
    float carry = (lane == 63) ? 0.f : t1;
#pragma unroll
    for (int j = 15; j >= 0; --j) { a[j] = dl[j] + c * carry; carry = a[j]; }

    // raw advantages, returns, whiten partials
    double sx = 0.0, sx2 = 0.0, nn = 0.0;
#pragma unroll
    for (int j = 0; j < 16; ++j) {
        const int t = lane * 16 + j;
        out[O_ADV + b * R_ + t] = a[j];
        out[O_RET + b * R_ + t] = a[j] + v[j];
        if (!((mbits >> j) & 1u)) {
            sx  += (double)a[j];
            sx2 += (double)a[j] * (double)a[j];
            nn  += 1.0;
        }
    }
#pragma unroll
    for (int d = 1; d < 64; d <<= 1) {
        sx  += __shfl_xor(sx, d, 64);
        sx2 += __shfl_xor(sx2, d, 64);
        nn  += __shfl_xor(nn, d, 64);
    }
    if (lane == 0) {
        atomicAdd(&acc[0], sx);
        atomicAdd(&acc[1], sx2);
        atomicAdd(&acc[2], nn);
        out[O_VLP + b] = (float)vlp;
        out[O_SC + b]  = score;
        out[O_RLP + b] = (float)rlp;
    }
}

// ---------------------------------------------------------------------------
// K3: masked whitening of advantages, in place on d_out.
// ---------------------------------------------------------------------------
__global__ __launch_bounds__(256) void k_whiten(
    float* __restrict__ out,
    const double* __restrict__ acc,
    const void* __restrict__ maskraw,
    const int* __restrict__ meta)
{
    const int i = blockIdx.x * blockDim.x + threadIdx.x;
    if (i >= B_ * R_) return;
    const double sx = acc[0], sx2 = acc[1], n = acc[2];
    const double mean = sx / n;
    const double var  = (sx2 - sx * sx / n) / (n - 1.0);
    const float  rs   = (float)(1.0 / sqrt(var + 1e-8));
    bool pad;
    if (meta[M_FLAG]) pad = ((const unsigned char*)maskraw)[i] != 0;
    else              pad = ((const int*)maskraw)[i] != 0;
    const float x = out[O_ADV + i];
    out[O_ADV + i] = pad ? 0.f : (x - (float)mean) * rs;
}

extern "C" void kernel_launch(void* const* d_in, const int* in_sizes, int n_in,
                              void* d_out, int out_size, void* d_ws, size_t ws_size,
                              hipStream_t stream) {
    const float* hidden = (const float*)d_in[0];
    const float* wb     = (const float*)d_in[1];
    const float* wa     = (const float*)d_in[2];
    const float* gen    = (const float*)d_in[3];
    const float* ref    = (const float*)d_in[4];
    const void*  mask   = d_in[5];
    // d_in[6] = queries_len (constant 512, baked in)

    float* out = (float*)d_out;
    float* wsf = (float*)d_ws;
    float* vals_dot   = wsf;
    float* scores_dot = wsf + NROW;
    int*    meta = (int*)((char*)d_ws + (size_t)2 * NROW * sizeof(float));
    double* acc  = (double*)((char*)d_ws + (size_t)2 * NROW * sizeof(float) + 512);

    hipMemsetAsync(acc, 0, 3 * sizeof(double), stream);
    hipLaunchKernelGGL(k_prep, dim3(1), dim3(1024), 0, stream, mask, meta);
    hipLaunchKernelGGL(k_dots, dim3(2048), dim3(256), 0, stream,
                       hidden, wb, wa, meta, vals_dot, scores_dot);
    hipLaunchKernelGGL(k_seq, dim3(B_), dim3(64), 0, stream,
                       vals_dot, scores_dot, gen, ref, mask, meta, out, acc);
    hipLaunchKernelGGL(k_whiten, dim3((B_ * R_ + 255) / 256), dim3(256), 0, stream,
                       out, acc, mask, meta);
}